// Round 5
// baseline (39.463 us; speedup 1.0000x reference)
//
#include <hip/hip_runtime.h>

#define BB 32
#define NN 2048
#define WW 64
#define CC 1024
#define NTAP 17
#define NB 512
#define EPSF 1e-8f
#define TOKEN 0x5A5A5A5Au

// ws float layout
#define WS_Q 0                      // [BB][NN] q = 0.5*gate*dir*alloc
#define WS_G (BB*NN)                // [BB] gate
#define WS_P (BB*NN + BB)           // [BB][2][2] (m_half, sumexp_half)
#define WS_F (BB*NN + BB + BB*4)    // u32 flags: [b]=alloc done, [BB + 2b+half]=sim partial done

// ---------------------------------------------------------------------------
// Single kernel, 96 blocks x 1024:
//  blocks 0..31  (b=bid): counting-bin alloc + shift/gate dots + dir conv.
//     writes out2 (dir), out3 (alloc), ws q/gate; release-publishes flag[b].
//  blocks 32..95 (idx=bid-32, b=idx>>1, half=idx&1): k/beta projection +
//     sim for rows half*1024+tid; block softmax partial; rendezvous with
//     sibling + alloc block; writes out1 (content), out0 (write_weights).
// ---------------------------------------------------------------------------
__global__ __launch_bounds__(1024) void k_all(
    const float* __restrict__ co, const float* __restrict__ rdw,
    const float* __restrict__ usage, const float* __restrict__ mem,
    const float* __restrict__ Wk, const float* __restrict__ bk,
    const float* __restrict__ Wb, const float* __restrict__ bb,
    const float* __restrict__ Ws, const float* __restrict__ bs,
    const float* __restrict__ Wg, const float* __restrict__ bg,
    float* __restrict__ ws, float* __restrict__ out)
{
    __shared__ float co_s[CC];                 // 4 KB (both paths)
    __shared__ __align__(16) float k_s[WW + 8];
    __shared__ float r_s[NN];                  // 8 KB alloc
    __shared__ unsigned long long skey[NN];    // 16 KB alloc
    __shared__ float slog[NN];                 // 8 KB alloc
    __shared__ float alloc_s[NN];              // 8 KB alloc
    __shared__ unsigned hist[NB];
    __shared__ float binlog[NB];
    __shared__ unsigned binStart[NB];
    __shared__ unsigned cursor[NB];
    __shared__ float binpre[NB];
    __shared__ unsigned uw[8];
    __shared__ float fw[8];
    __shared__ float dot4[16][4];
    __shared__ float sred[16];
    __shared__ float scalars[8];
    __shared__ float wd_s[NTAP];
    __shared__ float bcast2[2];

    const int tid = threadIdx.x, wave = tid >> 6, lane = tid & 63;
    unsigned* flags = (unsigned*)(ws + WS_F);

    if (blockIdx.x < BB) {
        // ======================= alloc + dots + dir =======================
        const int b = blockIdx.x;
        if (tid < NB) { hist[tid] = 0u; binlog[tid] = 0.f; }
        co_s[tid] = co[(size_t)b * CC + tid];
        r_s[tid]        = rdw[(size_t)b * NN + tid];
        r_s[tid + 1024] = rdw[(size_t)b * NN + tid + 1024];
        float u0 = usage[(size_t)b * NN + tid];
        float u1 = usage[(size_t)b * NN + tid + 1024];
        __syncthreads();
        float lg0 = log1pf(-u0), lg1 = log1pf(-u1);
        int bin0 = (int)(u0 * NB); bin0 = bin0 < 0 ? 0 : (bin0 > NB - 1 ? NB - 1 : bin0);
        int bin1 = (int)(u1 * NB); bin1 = bin1 < 0 ? 0 : (bin1 > NB - 1 ? NB - 1 : bin1);
        atomicAdd(&hist[bin0], 1u); atomicAdd(&binlog[bin0], lg0);
        atomicAdd(&hist[bin1], 1u); atomicAdd(&binlog[bin1], lg1);
        {
            float cv = co_s[tid];
            float p0 = cv * Ws[tid], p1 = cv * Ws[CC + tid],
                  p2 = cv * Ws[2 * CC + tid], p3 = cv * Wg[tid];
            #pragma unroll
            for (int off = 32; off; off >>= 1) {
                p0 += __shfl_xor(p0, off); p1 += __shfl_xor(p1, off);
                p2 += __shfl_xor(p2, off); p3 += __shfl_xor(p3, off);
            }
            if (lane == 0) {
                dot4[wave][0] = p0; dot4[wave][1] = p1;
                dot4[wave][2] = p2; dot4[wave][3] = p3;
            }
        }
        __syncthreads();
        unsigned hv = 0u; float bv = 0.f, fi = 0.f; unsigned ui = 0u;
        if (tid < NB) {
            hv = hist[tid]; bv = binlog[tid];
            ui = hv; fi = bv;
            #pragma unroll
            for (int off = 1; off < 64; off <<= 1) {
                unsigned tu = __shfl_up(ui, off);
                float    tf = __shfl_up(fi, off);
                if (lane >= off) { ui += tu; fi += tf; }
            }
            if (lane == 63) { uw[wave] = ui; fw[wave] = fi; }
        }
        if (tid < 4) {
            float s = 0.f;
            #pragma unroll
            for (int w = 0; w < 16; w++) s += dot4[w][tid];
            scalars[tid] = s + ((tid < 3) ? bs[tid] : bg[0]);
        }
        __syncthreads();
        if (tid < 8) {
            unsigned v = uw[tid]; float f = fw[tid];
            #pragma unroll
            for (int off = 1; off < 8; off <<= 1) {
                unsigned tu = __shfl_up(v, off);
                float    tf = __shfl_up(f, off);
                if (tid >= off) { v += tu; f += tf; }
            }
            uw[tid] = v; fw[tid] = f;
        } else if (tid == 16) {
            float g = scalars[3];
            float gate = 1.f / (1.f + __expf(-g));
            scalars[6] = gate;
            ws[WS_G + b] = gate;
            float s0 = scalars[0], s1 = scalars[1], s2 = scalars[2];
            float m = fmaxf(s0, fmaxf(s1, s2));
            float e0 = __expf(s0 - m), e1 = __expf(s1 - m), e2 = __expf(s2 - m);
            float inv = 1.f / (e0 + e1 + e2);
            float sc = (e2 - e0) * inv;
            float den = 2.f * sc * sc + EPSF;
            float w[NTAP]; float S = 0.f;
            #pragma unroll
            for (int d = 0; d < NTAP; d++) { w[d] = __expf(-(float)(d * d) / den); S += w[d]; }
            float invS = 1.f / (S + EPSF);
            #pragma unroll
            for (int d = 0; d < NTAP; d++) wd_s[d] = w[d] * invS;
        }
        __syncthreads();
        if (tid < NB) {
            unsigned woff = wave ? uw[wave - 1] : 0u;
            float    foff = wave ? fw[wave - 1] : 0.f;
            unsigned st = woff + ui - hv;
            binStart[tid] = st; cursor[tid] = st;
            binpre[tid] = foff + fi - bv;
        }
        __syncthreads();
        unsigned long long key0 = ((unsigned long long)__float_as_uint(u0) << 32) | (unsigned)tid;
        unsigned long long key1 = ((unsigned long long)__float_as_uint(u1) << 32) | (unsigned)(tid + 1024);
        {
            unsigned p0 = atomicAdd(&cursor[bin0], 1u);
            skey[p0] = key0; slog[p0] = lg0;
            unsigned p1 = atomicAdd(&cursor[bin1], 1u);
            skey[p1] = key1; slog[p1] = lg1;
        }
        __syncthreads();
        float* aout = out + 3 * (size_t)BB * NN + (size_t)b * NN;
        #pragma unroll
        for (int pp = 0; pp < 2; pp++) {
            int p = tid + pp * 1024;
            unsigned long long kp = skey[p];
            float up = __uint_as_float((unsigned)(kp >> 32));
            int c = (int)(up * NB); c = c < 0 ? 0 : (c > NB - 1 ? NB - 1 : c);
            unsigned st = binStart[c], cnt = hist[c];
            float s = binpre[c];
            for (unsigned q = 0; q < cnt; q++)
                s += (skey[st + q] <= kp) ? slog[st + q] : 0.f;
            float a = __expf(s);
            unsigned oidx = (unsigned)(kp & 0xFFFFFFFFu);
            alloc_s[oidx] = a;
            aout[oidx] = a;
        }
        __syncthreads();
        const float gate = scalars[6];
        float dw0 = 0.f, dw1 = 0.f;
        #pragma unroll
        for (int d = 0; d < NTAP; d++) {
            float w = wd_s[d];
            dw0 = fmaf(w, r_s[(tid + 1024 + d) & (NN - 1)], dw0);
            dw1 = fmaf(w, r_s[(tid + d) & (NN - 1)], dw1);
        }
        out[2 * (size_t)BB * NN + (size_t)b * NN + tid]        = dw0;
        out[2 * (size_t)BB * NN + (size_t)b * NN + tid + 1024] = dw1;
        ws[WS_Q + (size_t)b * NN + tid]        = 0.5f * gate * dw0 * alloc_s[tid];
        ws[WS_Q + (size_t)b * NN + tid + 1024] = 0.5f * gate * dw1 * alloc_s[tid + 1024];
        __syncthreads();                       // all global writes drained (vmcnt0 at barrier)
        if (tid == 0) {
            __threadfence();                   // flush L2 -> LLC (release)
            atomicExch(&flags[b], TOKEN);
        }
    } else {
        // ======================= sim + content + final =======================
        const int idx = blockIdx.x - BB;
        const int b = idx >> 1, half = idx & 1;
        const int row = half * 1024 + tid;
        co_s[tid] = co[(size_t)b * CC + tid];
        __syncthreads();

        // prefetch own memory row (16 x float4 in flight across projection)
        const float4* mrow = reinterpret_cast<const float4*>(
            mem + ((size_t)b * NN + row) * WW);
        float4 mr[16];
        #pragma unroll
        for (int i = 0; i < 16; ++i) mr[i] = mrow[i];

        // k projection: wave w -> rows w, w+16, w+32, w+48 (float4 loads)
        const float4* co4 = reinterpret_cast<const float4*>(co_s);
        #pragma unroll
        for (int rr = 0; rr < 4; ++rr) {
            const int o = wave + rr * 16;
            const float4* wrow = reinterpret_cast<const float4*>(Wk + (size_t)o * CC);
            float s = 0.f;
            #pragma unroll
            for (int ch = 0; ch < 4; ++ch) {
                float4 wv = wrow[ch * 64 + lane];
                float4 cv = co4[ch * 64 + lane];
                s += wv.x * cv.x + wv.y * cv.y + wv.z * cv.z + wv.w * cv.w;
            }
            #pragma unroll
            for (int off = 32; off; off >>= 1) s += __shfl_xor(s, off);
            if (lane == 0) k_s[o] = tanhf(s + bk[o]);
        }
        if (wave == 0) {
            const float4* wrow = reinterpret_cast<const float4*>(Wb);
            float s = 0.f;
            #pragma unroll
            for (int ch = 0; ch < 4; ++ch) {
                float4 wv = wrow[ch * 64 + lane];
                float4 cv = co4[ch * 64 + lane];
                s += wv.x * cv.x + wv.y * cv.y + wv.z * cv.z + wv.w * cv.w;
            }
            #pragma unroll
            for (int off = 32; off; off >>= 1) s += __shfl_xor(s, off);
            if (lane == 0) k_s[WW] = s + bb[0];
        }
        __syncthreads();

        float xb = k_s[WW];
        const float beta = (xb > 20.f) ? xb : log1pf(__expf(xb));
        const float4* k4 = reinterpret_cast<const float4*>(k_s);
        float acc = 0.f;
        #pragma unroll
        for (int i = 0; i < 16; ++i)
            acc += mr[i].x * k4[i].x + mr[i].y * k4[i].y
                 + mr[i].z * k4[i].z + mr[i].w * k4[i].w;
        const float x = acc * beta;

        // block-local softmax partial (m_half, sum_half)
        float m = x;
        #pragma unroll
        for (int off = 32; off; off >>= 1) m = fmaxf(m, __shfl_xor(m, off));
        if (lane == 0) sred[wave] = m;
        __syncthreads();
        if (tid < 16) {
            float v = sred[tid];
            v = fmaxf(v, __shfl_xor(v, 1)); v = fmaxf(v, __shfl_xor(v, 2));
            v = fmaxf(v, __shfl_xor(v, 4)); v = fmaxf(v, __shfl_xor(v, 8));
            if (tid == 0) bcast2[0] = v;
        }
        __syncthreads();
        const float Mh = bcast2[0];
        const float e = __expf(x - Mh);
        float ssum = e;
        #pragma unroll
        for (int off = 32; off; off >>= 1) ssum += __shfl_xor(ssum, off);
        if (lane == 0) sred[wave] = ssum;
        __syncthreads();
        if (tid < 16) {
            float v = sred[tid];
            v += __shfl_xor(v, 1); v += __shfl_xor(v, 2);
            v += __shfl_xor(v, 4); v += __shfl_xor(v, 8);
            if (tid == 0) {
                const float Sh = v;
                float* pp = ws + WS_P + ((size_t)b * 2 + half) * 2;
                pp[0] = Mh; pp[1] = Sh;
                __threadfence();                       // release partial
                atomicExch(&flags[BB + b * 2 + half], TOKEN);
                // rendezvous: sibling partial + alloc results
                unsigned* fsib = &flags[BB + b * 2 + (half ^ 1)];
                while (atomicAdd(fsib, 0u) != TOKEN) __builtin_amdgcn_s_sleep(2);
                while (atomicAdd(&flags[b], 0u) != TOKEN) __builtin_amdgcn_s_sleep(2);
                __threadfence();                       // acquire (inv L1/L2)
                const float* ps = ws + WS_P + ((size_t)b * 2 + (half ^ 1)) * 2;
                float Ms = ps[0], Ss = ps[1];
                float M = fmaxf(Mh, Ms);
                float denom = Sh * __expf(Mh - M) + Ss * __expf(Ms - M);
                bcast2[0] = __expf(Mh - M) / denom;    // factor f: c = e * f
                bcast2[1] = ws[WS_G + b];              // gate
            }
        }
        __syncthreads();
        __threadfence();    // ensure q reads below see alloc's flushed data
        const float f = bcast2[0], gate = bcast2[1];
        const float c = e * f;
        out[(size_t)BB * NN + (size_t)b * NN + row] = c;
        const float q = ws[WS_Q + (size_t)b * NN + row];
        out[(size_t)b * NN + row] = fmaf(0.5f * gate, c, q);
    }
}

extern "C" void kernel_launch(void* const* d_in, const int* in_sizes, int n_in,
                              void* d_out, int out_size, void* d_ws, size_t ws_size,
                              hipStream_t stream) {
    const float* co    = (const float*)d_in[0];
    const float* rdw   = (const float*)d_in[1];
    const float* mem   = (const float*)d_in[3];
    const float* usage = (const float*)d_in[4];
    const float* Wk    = (const float*)d_in[5];
    const float* bk    = (const float*)d_in[6];
    const float* Wb    = (const float*)d_in[7];
    const float* bb    = (const float*)d_in[8];
    const float* Ws_   = (const float*)d_in[9];
    const float* bs    = (const float*)d_in[10];
    const float* Wg    = (const float*)d_in[11];
    const float* bg    = (const float*)d_in[12];
    float* out = (float*)d_out;
    float* wsf = (float*)d_ws;

    hipLaunchKernelGGL(k_all, dim3(BB + 2 * BB), dim3(1024), 0, stream,
                       co, rdw, usage, mem, Wk, bk, Wb, bb, Ws_, bs, Wg, bg,
                       wsf, out);
}

// Round 6
// 30.319 us; speedup vs baseline: 1.3016x; 1.3016x over previous
//
#include <hip/hip_runtime.h>

#define BB 32
#define NN 2048
#define WW 64
#define CC 1024
#define NTAP 17
#define NB 512
#define EPSF 1e-8f

// ---------------------------------------------------------------------------
// Single kernel: 32 blocks x 1024, block b = batch b, everything in LDS.
//   P0 loads -> P1 (hist atomics + all projections) -> P2 scans/taps ->
//   P3 scatter -> P4 masked log-sums (alloc) -> P5 sim -> P6 softmax ->
//   P7 conv + combine. No workspace, no cross-block sync.
// alloc[i] = exp( prefix_logsum(bins<bin(i)) + masked sum in own bin ), exact
// vs jnp stable argsort (u64 key (bits(u)<<32)|idx; bin=floor(u*NB) monotone).
// ---------------------------------------------------------------------------
__global__ __launch_bounds__(1024, 4) void k_fused(
    const float* __restrict__ co, const float* __restrict__ rdw,
    const float* __restrict__ usage, const float* __restrict__ mem,
    const float* __restrict__ Wk, const float* __restrict__ bk,
    const float* __restrict__ Wb, const float* __restrict__ bb,
    const float* __restrict__ Ws, const float* __restrict__ bs,
    const float* __restrict__ Wg, const float* __restrict__ bg,
    float* __restrict__ out)
{
    __shared__ float co_s[CC];                  // 4 KB
    __shared__ __align__(16) float k_s[WW + 4]; // [64]=beta logit, [65]=beta
    __shared__ float r_s[NN];                   // 8 KB
    __shared__ unsigned long long skey[NN];     // 16 KB
    __shared__ float slog[NN];                  // 8 KB; reused as x_s after P4
    __shared__ float alloc_s[NN];               // 8 KB
    __shared__ unsigned hist[NB];               // 2 KB
    __shared__ float binlog[NB];                // 2 KB
    __shared__ unsigned binStart[NB];           // 2 KB
    __shared__ unsigned cursor[NB];             // 2 KB
    __shared__ float binpre[NB];                // 2 KB
    __shared__ unsigned uw[8];
    __shared__ float fw[8];
    __shared__ float dot4[16][4];
    __shared__ float sred[16];
    __shared__ float scalars[8];                // 0..2 shift logits, 3 gate logit, 6 gate
    __shared__ float wd_s[NTAP];
    __shared__ float bcast[2];

    const int tid = threadIdx.x, wave = tid >> 6, lane = tid & 63;
    const int b = blockIdx.x;

    // ---- P0: loads ----
    if (tid < NB) { hist[tid] = 0u; binlog[tid] = 0.f; }
    co_s[tid] = co[(size_t)b * CC + tid];
    r_s[tid]        = rdw[(size_t)b * NN + tid];
    r_s[tid + 1024] = rdw[(size_t)b * NN + tid + 1024];
    float u0 = usage[(size_t)b * NN + tid];
    float u1 = usage[(size_t)b * NN + tid + 1024];
    __syncthreads();

    // ---- P1: hist/logsum atomics + shift/gate partials + k/beta projection ----
    float lg0 = log1pf(-u0), lg1 = log1pf(-u1);
    int bin0 = (int)(u0 * NB); bin0 = bin0 < 0 ? 0 : (bin0 > NB - 1 ? NB - 1 : bin0);
    int bin1 = (int)(u1 * NB); bin1 = bin1 < 0 ? 0 : (bin1 > NB - 1 ? NB - 1 : bin1);
    atomicAdd(&hist[bin0], 1u); atomicAdd(&binlog[bin0], lg0);
    atomicAdd(&hist[bin1], 1u); atomicAdd(&binlog[bin1], lg1);
    {
        float cv = co_s[tid];
        float p0 = cv * Ws[tid], p1 = cv * Ws[CC + tid],
              p2 = cv * Ws[2 * CC + tid], p3 = cv * Wg[tid];
        #pragma unroll
        for (int off = 32; off; off >>= 1) {
            p0 += __shfl_xor(p0, off); p1 += __shfl_xor(p1, off);
            p2 += __shfl_xor(p2, off); p3 += __shfl_xor(p3, off);
        }
        if (lane == 0) {
            dot4[wave][0] = p0; dot4[wave][1] = p1;
            dot4[wave][2] = p2; dot4[wave][3] = p3;
        }
    }
    for (int o = wave; o < 65; o += 16) {
        const float* row = (o < 64) ? (Wk + (size_t)o * CC) : Wb;
        float s = 0.f;
        #pragma unroll 4
        for (int c = lane; c < CC; c += 64) s = fmaf(co_s[c], row[c], s);
        #pragma unroll
        for (int off = 32; off; off >>= 1) s += __shfl_xor(s, off);
        if (lane == 0) {
            if (o < 64) k_s[o] = tanhf(s + bk[o]);
            else        k_s[WW] = s + bb[0];
        }
    }
    __syncthreads();

    // ---- P2a: dual wave-scan (hist u32 / binlog f32) + finish small dots ----
    unsigned hv = 0u; float bv = 0.f, fi = 0.f; unsigned ui = 0u;
    if (tid < NB) {
        hv = hist[tid]; bv = binlog[tid];
        ui = hv; fi = bv;
        #pragma unroll
        for (int off = 1; off < 64; off <<= 1) {
            unsigned tu = __shfl_up(ui, off);
            float    tf = __shfl_up(fi, off);
            if (lane >= off) { ui += tu; fi += tf; }
        }
        if (lane == 63) { uw[wave] = ui; fw[wave] = fi; }
    }
    if (tid < 4) {
        float s = 0.f;
        #pragma unroll
        for (int w = 0; w < 16; w++) s += dot4[w][tid];
        scalars[tid] = s + ((tid < 3) ? bs[tid] : bg[0]);
    }
    __syncthreads();
    // ---- P2b: cross-wave scan || gate+taps || beta ----
    if (tid < 8) {
        unsigned v = uw[tid]; float f = fw[tid];
        #pragma unroll
        for (int off = 1; off < 8; off <<= 1) {
            unsigned tu = __shfl_up(v, off);
            float    tf = __shfl_up(f, off);
            if (tid >= off) { v += tu; f += tf; }
        }
        uw[tid] = v; fw[tid] = f;
    } else if (tid == 16) {
        float g = scalars[3];
        scalars[6] = 1.f / (1.f + __expf(-g));          // gate
        float s0 = scalars[0], s1 = scalars[1], s2 = scalars[2];
        float m = fmaxf(s0, fmaxf(s1, s2));
        float e0 = __expf(s0 - m), e1 = __expf(s1 - m), e2 = __expf(s2 - m);
        float inv = 1.f / (e0 + e1 + e2);
        float sc = (e2 - e0) * inv;
        float den = 2.f * sc * sc + EPSF;
        float w[NTAP]; float S = 0.f;
        #pragma unroll
        for (int d = 0; d < NTAP; d++) { w[d] = __expf(-(float)(d * d) / den); S += w[d]; }
        float invS = 1.f / (S + EPSF);
        #pragma unroll
        for (int d = 0; d < NTAP; d++) wd_s[d] = w[d] * invS;
    } else if (tid == 17) {
        float xb = k_s[WW];
        k_s[WW + 1] = (xb > 20.f) ? xb : log1pf(__expf(xb));   // beta
    }
    __syncthreads();
    // ---- P2c: per-bin bases ----
    if (tid < NB) {
        unsigned woff = wave ? uw[wave - 1] : 0u;
        float    foff = wave ? fw[wave - 1] : 0.f;
        unsigned st = woff + ui - hv;
        binStart[tid] = st; cursor[tid] = st;
        binpre[tid] = foff + fi - bv;
    }
    __syncthreads();

    // ---- P3: scatter (key, log) into bin segments ----
    unsigned long long key0 = ((unsigned long long)__float_as_uint(u0) << 32) | (unsigned)tid;
    unsigned long long key1 = ((unsigned long long)__float_as_uint(u1) << 32) | (unsigned)(tid + 1024);
    {
        unsigned p0 = atomicAdd(&cursor[bin0], 1u);
        skey[p0] = key0; slog[p0] = lg0;
        unsigned p1 = atomicAdd(&cursor[bin1], 1u);
        skey[p1] = key1; slog[p1] = lg1;
    }
    __syncthreads();

    // ---- P4: masked sums -> alloc_s + out3 ----
    float* aout = out + 3 * (size_t)BB * NN + (size_t)b * NN;
    #pragma unroll
    for (int pp = 0; pp < 2; pp++) {
        int p = tid + pp * 1024;
        unsigned long long kp = skey[p];
        float up = __uint_as_float((unsigned)(kp >> 32));
        int c = (int)(up * NB); c = c < 0 ? 0 : (c > NB - 1 ? NB - 1 : c);
        unsigned st = binStart[c], cnt = hist[c];
        float s = binpre[c];
        for (unsigned q = 0; q < cnt; q++)
            s += (skey[st + q] <= kp) ? slog[st + q] : 0.f;
        float a = __expf(s);
        unsigned oidx = (unsigned)(kp & 0xFFFFFFFFu);
        alloc_s[oidx] = a;
        aout[oidx] = a;
    }
    __syncthreads();                 // skey/slog dead; slog reused as x_s

    // ---- P5: sim (16 lanes/row, 32 iters, coalesced float4) ----
    {
        const float beta = k_s[WW + 1];
        const int lane16 = tid & 15, group = tid >> 4;   // 64 groups
        const float4 k4 = reinterpret_cast<const float4*>(k_s)[lane16];
        float* x_s = slog;
        #pragma unroll 4
        for (int it = 0; it < 32; ++it) {
            const int row = it * 64 + group;
            const float4 m4 = *reinterpret_cast<const float4*>(
                mem + ((size_t)b * NN + row) * WW + lane16 * 4);
            float s = m4.x * k4.x + m4.y * k4.y + m4.z * k4.z + m4.w * k4.w;
            s += __shfl_xor(s, 1); s += __shfl_xor(s, 2);
            s += __shfl_xor(s, 4); s += __shfl_xor(s, 8);
            if (lane16 == 0) x_s[row] = s * beta;
        }
    }
    __syncthreads();

    // ---- P6: block softmax over x_s[0..2047] ----
    const float x0 = slog[tid], x1 = slog[tid + 1024];
    float m = fmaxf(x0, x1);
    #pragma unroll
    for (int off = 32; off; off >>= 1) m = fmaxf(m, __shfl_xor(m, off));
    if (lane == 0) sred[wave] = m;
    __syncthreads();
    if (tid < 16) {
        float v = sred[tid];
        v = fmaxf(v, __shfl_xor(v, 1)); v = fmaxf(v, __shfl_xor(v, 2));
        v = fmaxf(v, __shfl_xor(v, 4)); v = fmaxf(v, __shfl_xor(v, 8));
        if (tid == 0) bcast[0] = v;
    }
    __syncthreads();
    const float M = bcast[0];
    const float e0 = __expf(x0 - M), e1 = __expf(x1 - M);
    float ssum = e0 + e1;
    #pragma unroll
    for (int off = 32; off; off >>= 1) ssum += __shfl_xor(ssum, off);
    if (lane == 0) sred[wave] = ssum;
    __syncthreads();
    if (tid < 16) {
        float v = sred[tid];
        v += __shfl_xor(v, 1); v += __shfl_xor(v, 2);
        v += __shfl_xor(v, 4); v += __shfl_xor(v, 8);
        if (tid == 0) bcast[1] = v;
    }
    __syncthreads();

    // ---- P7: content + directional + combine ----
    const float inv = 1.f / bcast[1];
    const float gate = scalars[6];
    const float c0 = e0 * inv, c1 = e1 * inv;
    out[(size_t)BB * NN + (size_t)b * NN + tid]        = c0;
    out[(size_t)BB * NN + (size_t)b * NN + tid + 1024] = c1;

    float dw0 = 0.f, dw1 = 0.f;
    #pragma unroll
    for (int d = 0; d < NTAP; d++) {
        float w = wd_s[d];
        dw0 = fmaf(w, r_s[(tid + 1024 + d) & (NN - 1)], dw0);
        dw1 = fmaf(w, r_s[(tid + d) & (NN - 1)], dw1);
    }
    out[2 * (size_t)BB * NN + (size_t)b * NN + tid]        = dw0;
    out[2 * (size_t)BB * NN + (size_t)b * NN + tid + 1024] = dw1;

    out[(size_t)b * NN + tid]        = gate * (0.5f * c0 + 0.5f * dw0 * alloc_s[tid]);
    out[(size_t)b * NN + tid + 1024] = gate * (0.5f * c1 + 0.5f * dw1 * alloc_s[tid + 1024]);
}

extern "C" void kernel_launch(void* const* d_in, const int* in_sizes, int n_in,
                              void* d_out, int out_size, void* d_ws, size_t ws_size,
                              hipStream_t stream) {
    const float* co    = (const float*)d_in[0];
    const float* rdw   = (const float*)d_in[1];
    const float* mem   = (const float*)d_in[3];
    const float* usage = (const float*)d_in[4];
    const float* Wk    = (const float*)d_in[5];
    const float* bk    = (const float*)d_in[6];
    const float* Wb    = (const float*)d_in[7];
    const float* bb    = (const float*)d_in[8];
    const float* Ws_   = (const float*)d_in[9];
    const float* bs    = (const float*)d_in[10];
    const float* Wg    = (const float*)d_in[11];
    const float* bg    = (const float*)d_in[12];
    float* out = (float*)d_out;

    hipLaunchKernelGGL(k_fused, dim3(BB), dim3(1024), 0, stream,
                       co, rdw, usage, mem, Wk, bk, Wb, bb, Ws_, bs, Wg, bg,
                       out);
}